// Round 4
// baseline (1525.356 us; speedup 1.0000x reference)
//
#include <hip/hip_runtime.h>
#include <hip/hip_bf16.h>

#define NN 500000
// feats = [mu_in(128) | mu_not(128) | enc(128)]; H1=256, H2=128, H3=64

typedef unsigned short ushort_t;
typedef __attribute__((ext_vector_type(8))) __bf16 bf16x8;
typedef __attribute__((ext_vector_type(2))) __bf16 bf16x2;
typedef __attribute__((ext_vector_type(4))) float f32x4;

__device__ inline ushort_t f2bf(float f) {
  union { float f; unsigned u; } x; x.f = f;
  return (ushort_t)((x.u + 0x7FFFu + ((x.u >> 16) & 1u)) >> 16);
}
__device__ inline float lrelu(float v) { return fmaxf(v, 0.f) + 0.01f * fminf(v, 0.f); }
__device__ inline unsigned pk2(float lo, float hi) {
  union { bf16x2 v; unsigned u; } x; x.v[0] = (__bf16)lo; x.v[1] = (__bf16)hi; return x.u;
}
#define SHF(v, s) ((unsigned)__shfl((int)(v), (s), 64))

// ---------------- K_colmax: masked per-column max over N rows ----------------
__global__ __launch_bounds__(256) void k_colmax(
    const float* __restrict__ enc, const int* __restrict__ cs,
    float* mu_in, float* mu_not)
{
  __shared__ float4 s_in[256], s_not[256];
  const int tid = threadIdx.x;
  const int c4 = tid & 31;    // float4-column 0..31
  const int rs = tid >> 5;    // row slice 0..7
  const long base = (long)blockIdx.x * 256;
  float4 mi = {0.f, 0.f, 0.f, 0.f}, mn = {0.f, 0.f, 0.f, 0.f};
  const float4* e4 = (const float4*)enc;
  #pragma unroll 4
  for (int it = 0; it < 32; ++it) {
    long r = base + rs + 8L * it;
    if (r < NN) {
      float4 v = e4[r * 32 + c4];
      bool ins = cs[r] > 0;
      mi.x = fmaxf(mi.x, ins ? v.x : 0.f); mi.y = fmaxf(mi.y, ins ? v.y : 0.f);
      mi.z = fmaxf(mi.z, ins ? v.z : 0.f); mi.w = fmaxf(mi.w, ins ? v.w : 0.f);
      mn.x = fmaxf(mn.x, ins ? 0.f : v.x); mn.y = fmaxf(mn.y, ins ? 0.f : v.y);
      mn.z = fmaxf(mn.z, ins ? 0.f : v.z); mn.w = fmaxf(mn.w, ins ? 0.f : v.w);
    }
  }
  s_in[tid] = mi; s_not[tid] = mn;
  __syncthreads();
  if (tid < 32) {
    for (int j = 1; j < 8; ++j) {
      float4 a = s_in[j * 32 + tid], b = s_not[j * 32 + tid];
      mi.x = fmaxf(mi.x, a.x); mi.y = fmaxf(mi.y, a.y);
      mi.z = fmaxf(mi.z, a.z); mi.w = fmaxf(mi.w, a.w);
      mn.x = fmaxf(mn.x, b.x); mn.y = fmaxf(mn.y, b.y);
      mn.z = fmaxf(mn.z, b.z); mn.w = fmaxf(mn.w, b.w);
    }
    // maxima are >= 0 so int-bit compare == float compare
    atomicMax((int*)&mu_in[4 * tid + 0], __float_as_int(mi.x));
    atomicMax((int*)&mu_in[4 * tid + 1], __float_as_int(mi.y));
    atomicMax((int*)&mu_in[4 * tid + 2], __float_as_int(mi.z));
    atomicMax((int*)&mu_in[4 * tid + 3], __float_as_int(mi.w));
    atomicMax((int*)&mu_not[4 * tid + 0], __float_as_int(mn.x));
    atomicMax((int*)&mu_not[4 * tid + 1], __float_as_int(mn.y));
    atomicMax((int*)&mu_not[4 * tid + 2], __float_as_int(mn.z));
    atomicMax((int*)&mu_not[4 * tid + 3], __float_as_int(mn.w));
  }
}

// ---------------- K_mlp: persistent, weights LDS-resident, barrier-free loop -------------
// 1024 threads = 16 waves (4/SIMD), 1 block/CU, grid 256. 16 rows/wave-iter.
// Interleaved per-mt-pair epilogue keeps live VGPRs ~120 (<=128 cap from
// __launch_bounds__(1024,4)) -- rounds 2/3 spilled at a 128-arch-VGPR allocation
// because 32-row accumulators alone needed 128 regs.
__global__ __launch_bounds__(1024, 4) void k_mlp(
    const float* __restrict__ enc,
    const float* __restrict__ W1, const float* __restrict__ b1,
    const float* __restrict__ W2, const float* __restrict__ b2,
    const float* __restrict__ W3, const float* __restrict__ b3,
    const float* __restrict__ W4, const float* __restrict__ b4,
    const float* __restrict__ mu_in, const float* __restrict__ mu_not,
    float* __restrict__ eL, float* __restrict__ psum)
{
  __shared__ ushort_t sW1[256 * 136];   // [n1][k=e]   69632 B
  __shared__ ushort_t sW2[128 * 264];   // [n2][k=n1]  67584 B
  __shared__ ushort_t sW3[64 * 136];    // [n3][k=n2]  17408 B
  __shared__ float sC[520];             // c[256]|b2[128]|b3[64]|W4[64]|b4
  __shared__ float sT[1024];            // cvec partials

  const int tid = threadIdx.x;

  // ---- one-time staging: fp32 global -> bf16 LDS (transposed; coalesced in n) ----
  for (int idx = tid; idx < 32768; idx += 1024) {
    int n = idx & 255, k = idx >> 8;              // n1, e
    sW1[n * 136 + k] = f2bf(W1[(256 + k) * 256 + n]);
  }
  for (int idx = tid; idx < 32768; idx += 1024) {
    int n = idx & 127, k = idx >> 7;              // n2, n1
    sW2[n * 264 + k] = f2bf(W2[k * 128 + n]);
  }
  for (int idx = tid; idx < 8192; idx += 1024) {
    int n = idx & 63, k = idx >> 6;               // n3, n2
    sW3[n * 136 + k] = f2bf(W3[k * 64 + n]);
  }
  if (tid >= 256 && tid < 384) sC[tid] = b2[tid - 256];
  else if (tid >= 384 && tid < 448) sC[tid] = b3[tid - 384];
  else if (tid >= 448 && tid < 512) sC[tid] = W4[tid - 448];
  if (tid == 0) sC[512] = b4[0];
  { // inlined cvec: c[j] = b1[j] + mu_in . W1[0:128,j] + mu_not . W1[128:256,j]
    const int j = tid & 255, h = tid >> 8;        // h = 0..3
    float c = h ? 0.f : b1[j];
    #pragma unroll 8
    for (int e = 32 * h; e < 32 * h + 32; ++e) {
      c += mu_in[e]  * W1[e * 256 + j];
      c += mu_not[e] * W1[(128 + e) * 256 + j];
    }
    sT[tid] = c;
  }
  __syncthreads();
  if (tid < 256) sC[tid] = sT[tid] + sT[tid + 256] + sT[tid + 512] + sT[tid + 768];
  __syncthreads();   // last block-wide barrier

  const int wave = tid >> 6, lane = tid & 63;
  const int lr = lane & 15, lg = lane >> 4;
  const int wid = blockIdx.x * 16 + wave;         // 0..4095
  const int selhi = lane & 32;
  const int srcLo = lr + ((lane & 16) << 1);      // butterfly partner lanes
  const int srcHi = srcLo + 16;

  const ushort_t* w1p = sW1 + lr * 136 + 8 * lg;  // + mt*2176 + kt*32
  const ushort_t* w2p = sW2 + lr * 264 + 8 * lg;  // + mt*4224 + kt*32
  const ushort_t* w3p = sW3 + lr * 136 + 8 * lg;

  float es = 0.f;
  bf16x8 B1[4];

  // preload + convert first 16-row group (row = wid*16 + lr, always < NN)
  {
    const float4* p = (const float4*)(enc + (size_t)(wid * 16 + lr) * 128);
    #pragma unroll
    for (int kt = 0; kt < 4; ++kt) {
      float4 f0 = p[kt * 8 + lg * 2], f1 = p[kt * 8 + lg * 2 + 1];
      bf16x8 a;
      a[0] = (__bf16)f0.x; a[1] = (__bf16)f0.y; a[2] = (__bf16)f0.z; a[3] = (__bf16)f0.w;
      a[4] = (__bf16)f1.x; a[5] = (__bf16)f1.y; a[6] = (__bf16)f1.z; a[7] = (__bf16)f1.w;
      B1[kt] = a;
    }
  }

  for (int r0 = wid * 16; r0 < NN; r0 += 65536) {
    // ---- L1: mt-pairs with immediate epilogue+butterfly -> B2[p] ----
    bf16x8 B2[8];
    #pragma unroll
    for (int p = 0; p < 8; ++p) {
      f32x4 a0 = (f32x4){0.f, 0.f, 0.f, 0.f}, a1 = (f32x4){0.f, 0.f, 0.f, 0.f};
      #pragma unroll
      for (int kt = 0; kt < 4; ++kt) {
        bf16x8 wA = *(const bf16x8*)(w1p + (2 * p) * 2176 + kt * 32);
        bf16x8 wB = *(const bf16x8*)(w1p + (2 * p + 1) * 2176 + kt * 32);
        a0 = __builtin_amdgcn_mfma_f32_16x16x32_bf16(wA, B1[kt], a0, 0, 0, 0);
        a1 = __builtin_amdgcn_mfma_f32_16x16x32_bf16(wB, B1[kt], a1, 0, 0, 0);
      }
      float4 cb0 = *(const float4*)(sC + 16 * (2 * p) + 4 * lg);
      float4 cb1 = *(const float4*)(sC + 16 * (2 * p + 1) + 4 * lg);
      unsigned q0 = pk2(lrelu(a0[0] + cb0.x), lrelu(a0[1] + cb0.y));
      unsigned q1 = pk2(lrelu(a0[2] + cb0.z), lrelu(a0[3] + cb0.w));
      unsigned q2 = pk2(lrelu(a1[0] + cb1.x), lrelu(a1[1] + cb1.y));
      unsigned q3 = pk2(lrelu(a1[2] + cb1.z), lrelu(a1[3] + cb1.w));
      unsigned w0a = SHF(q0, srcLo), w0b = SHF(q2, srcLo);
      unsigned w1a = SHF(q1, srcLo), w1b = SHF(q3, srcLo);
      unsigned w2a = SHF(q0, srcHi), w2b = SHF(q2, srcHi);
      unsigned w3a = SHF(q1, srcHi), w3b = SHF(q3, srcHi);
      union { unsigned w[4]; bf16x8 v; } u;
      u.w[0] = selhi ? w0b : w0a; u.w[1] = selhi ? w1b : w1a;
      u.w[2] = selhi ? w2b : w2a; u.w[3] = selhi ? w3b : w3a;
      B2[p] = u.v;
    }
    // ---- prefetch next 16-row group (B1 is dead now; consumed ~L4, far away) ----
    int rn = r0 + 65536; if (rn >= NN) rn = r0;   // last iter: dummy reload
    float4 tA[8];
    {
      const float4* p = (const float4*)(enc + (size_t)(rn + lr) * 128);
      #pragma unroll
      for (int kt = 0; kt < 4; ++kt) {
        tA[2 * kt]     = p[kt * 8 + lg * 2];
        tA[2 * kt + 1] = p[kt * 8 + lg * 2 + 1];
      }
    }
    // ---- L2: mt-pairs -> B3[p] ----
    bf16x8 B3[4];
    #pragma unroll
    for (int p = 0; p < 4; ++p) {
      f32x4 a0 = (f32x4){0.f, 0.f, 0.f, 0.f}, a1 = (f32x4){0.f, 0.f, 0.f, 0.f};
      #pragma unroll
      for (int kt = 0; kt < 8; ++kt) {
        bf16x8 wA = *(const bf16x8*)(w2p + (2 * p) * 4224 + kt * 32);
        bf16x8 wB = *(const bf16x8*)(w2p + (2 * p + 1) * 4224 + kt * 32);
        a0 = __builtin_amdgcn_mfma_f32_16x16x32_bf16(wA, B2[kt], a0, 0, 0, 0);
        a1 = __builtin_amdgcn_mfma_f32_16x16x32_bf16(wB, B2[kt], a1, 0, 0, 0);
      }
      float4 cb0 = *(const float4*)(sC + 256 + 16 * (2 * p) + 4 * lg);
      float4 cb1 = *(const float4*)(sC + 256 + 16 * (2 * p + 1) + 4 * lg);
      unsigned q0 = pk2(lrelu(a0[0] + cb0.x), lrelu(a0[1] + cb0.y));
      unsigned q1 = pk2(lrelu(a0[2] + cb0.z), lrelu(a0[3] + cb0.w));
      unsigned q2 = pk2(lrelu(a1[0] + cb1.x), lrelu(a1[1] + cb1.y));
      unsigned q3 = pk2(lrelu(a1[2] + cb1.z), lrelu(a1[3] + cb1.w));
      unsigned w0a = SHF(q0, srcLo), w0b = SHF(q2, srcLo);
      unsigned w1a = SHF(q1, srcLo), w1b = SHF(q3, srcLo);
      unsigned w2a = SHF(q0, srcHi), w2b = SHF(q2, srcHi);
      unsigned w3a = SHF(q1, srcHi), w3b = SHF(q3, srcHi);
      union { unsigned w[4]; bf16x8 v; } u;
      u.w[0] = selhi ? w0b : w0a; u.w[1] = selhi ? w1b : w1a;
      u.w[2] = selhi ? w2b : w2a; u.w[3] = selhi ? w3b : w3a;
      B3[p] = u.v;
    }
    // ---- L3 (mt-pairs) + L4 epilogue folded into W4 dot ----
    float dot = 0.f;
    #pragma unroll
    for (int p = 0; p < 2; ++p) {
      f32x4 a0 = (f32x4){0.f, 0.f, 0.f, 0.f}, a1 = (f32x4){0.f, 0.f, 0.f, 0.f};
      #pragma unroll
      for (int kt = 0; kt < 4; ++kt) {
        bf16x8 wA = *(const bf16x8*)(w3p + (2 * p) * 2176 + kt * 32);
        bf16x8 wB = *(const bf16x8*)(w3p + (2 * p + 1) * 2176 + kt * 32);
        a0 = __builtin_amdgcn_mfma_f32_16x16x32_bf16(wA, B3[kt], a0, 0, 0, 0);
        a1 = __builtin_amdgcn_mfma_f32_16x16x32_bf16(wB, B3[kt], a1, 0, 0, 0);
      }
      float4 cb0  = *(const float4*)(sC + 384 + 16 * (2 * p) + 4 * lg);
      float4 cb1  = *(const float4*)(sC + 384 + 16 * (2 * p + 1) + 4 * lg);
      float4 w4v0 = *(const float4*)(sC + 448 + 16 * (2 * p) + 4 * lg);
      float4 w4v1 = *(const float4*)(sC + 448 + 16 * (2 * p + 1) + 4 * lg);
      dot += lrelu(a0[0] + cb0.x) * w4v0.x + lrelu(a0[1] + cb0.y) * w4v0.y
           + lrelu(a0[2] + cb0.z) * w4v0.z + lrelu(a0[3] + cb0.w) * w4v0.w;
      dot += lrelu(a1[0] + cb1.x) * w4v1.x + lrelu(a1[1] + cb1.y) * w4v1.y
           + lrelu(a1[2] + cb1.z) * w4v1.z + lrelu(a1[3] + cb1.w) * w4v1.w;
    }
    dot += __shfl_xor(dot, 16, 64);
    dot += __shfl_xor(dot, 32, 64);
    float ev = expf(dot + sC[512]);
    if (lg == 0) eL[r0 + lr] = ev;
    es += ev;                        // 4x duplicated across lg, scaled at the end
    // ---- convert prefetched rows -> B1 for next iteration ----
    #pragma unroll
    for (int kt = 0; kt < 4; ++kt) {
      float4 f0 = tA[2 * kt], f1 = tA[2 * kt + 1];
      bf16x8 a;
      a[0] = (__bf16)f0.x; a[1] = (__bf16)f0.y; a[2] = (__bf16)f0.z; a[3] = (__bf16)f0.w;
      a[4] = (__bf16)f1.x; a[5] = (__bf16)f1.y; a[6] = (__bf16)f1.z; a[7] = (__bf16)f1.w;
      B1[kt] = a;
    }
  }
  // wave-wide partial softmax denominator (deterministic: one slot per wave)
  #pragma unroll
  for (int off = 1; off < 64; off <<= 1) es += __shfl_xor(es, off, 64);
  if (lane == 0) psum[wid] = 0.25f * es;
}

// ---------------- final reduce + normalize ----------------
__global__ __launch_bounds__(256) void k_finalsum(const float* __restrict__ psum,
                                                  float* __restrict__ scal)
{
  const int tid = threadIdx.x;
  float s = 0.f;
  #pragma unroll
  for (int k = 0; k < 16; ++k) s += psum[tid + k * 256];
  #pragma unroll
  for (int off = 1; off < 64; off <<= 1) s += __shfl_xor(s, off, 64);
  __shared__ float sr[4];
  if ((tid & 63) == 0) sr[tid >> 6] = s;
  __syncthreads();
  if (tid == 0) scal[0] = 1.f / (sr[0] + sr[1] + sr[2] + sr[3]);
}

__global__ __launch_bounds__(256) void k_norm(const float* __restrict__ eL,
                                              const float* __restrict__ scal,
                                              float* __restrict__ out)
{
  const float inv = scal[0];
  const int i = blockIdx.x * 256 + threadIdx.x;
  if (i < NN / 4) {
    float4 v = ((const float4*)eL)[i];
    float4 o = {v.x * inv, v.y * inv, v.z * inv, v.w * inv};
    ((float4*)out)[i] = o;
  }
}

extern "C" void kernel_launch(void* const* d_in, const int* in_sizes, int n_in,
                              void* d_out, int out_size, void* d_ws, size_t ws_size,
                              hipStream_t stream) {
  const float* enc = (const float*)d_in[0];
  const int*   cs  = (const int*)d_in[1];
  const float* W1  = (const float*)d_in[2];
  const float* b1  = (const float*)d_in[3];
  const float* W2  = (const float*)d_in[4];
  const float* b2  = (const float*)d_in[5];
  const float* W3  = (const float*)d_in[6];
  const float* b3  = (const float*)d_in[7];
  const float* W4  = (const float*)d_in[8];
  const float* b4  = (const float*)d_in[9];
  float* out = (float*)d_out;

  char* ws = (char*)d_ws;
  float* mu_in  = (float*)(ws + 0);        // 512 B
  float* mu_not = (float*)(ws + 512);      // 512 B
  float* psum   = (float*)(ws + 2048);     // 4096 floats = 16 KB
  float* scal   = (float*)(ws + 20480);    // 4 B
  float* eLbuf  = (float*)(ws + 24576);    // 2 MB (exp(logit) per row)

  hipMemsetAsync(ws, 0, 1024, stream);  // zero mu_in/mu_not (identity for max >= 0)

  k_colmax<<<dim3(1954), dim3(256), 0, stream>>>(enc, cs, mu_in, mu_not);
  k_mlp<<<dim3(256), dim3(1024), 0, stream>>>(enc, W1, b1, W2, b2, W3, b3, W4, b4,
                                              mu_in, mu_not, eLbuf, psum);
  k_finalsum<<<dim3(1), dim3(256), 0, stream>>>(psum, scal);
  k_norm<<<dim3(489), dim3(256), 0, stream>>>(eLbuf, scal, out);
}

// Round 5
// 1312.410 us; speedup vs baseline: 1.1623x; 1.1623x over previous
//
#include <hip/hip_runtime.h>
#include <hip/hip_bf16.h>

#define NN 500000
// feats = [mu_in(128) | mu_not(128) | enc(128)]; H1=256, H2=128, H3=64

typedef unsigned short ushort_t;
typedef __attribute__((ext_vector_type(8))) __bf16 bf16x8;
typedef __attribute__((ext_vector_type(2))) __bf16 bf16x2;
typedef __attribute__((ext_vector_type(4))) float f32x4;
typedef __attribute__((ext_vector_type(4))) unsigned uint4v;

__device__ inline ushort_t f2bf(float f) {
  unsigned u = __builtin_bit_cast(unsigned, f);
  return (ushort_t)((u + 0x7FFFu + ((u >> 16) & 1u)) >> 16);
}
__device__ inline float lrelu(float v) { return fmaxf(v, 0.f) + 0.01f * fminf(v, 0.f); }
__device__ inline unsigned pk2(float lo, float hi) {
  bf16x2 v; v[0] = (__bf16)lo; v[1] = (__bf16)hi;
  return __builtin_bit_cast(unsigned, v);
}
__device__ inline bf16x8 mk8(unsigned w0, unsigned w1, unsigned w2, unsigned w3) {
  uint4v u; u.x = w0; u.y = w1; u.z = w2; u.w = w3;
  return __builtin_bit_cast(bf16x8, u);
}
#define SHF(v, s) ((unsigned)__shfl((int)(v), (s), 64))

// ---------------- K_colmax: masked per-column max over N rows ----------------
__global__ __launch_bounds__(256) void k_colmax(
    const float* __restrict__ enc, const int* __restrict__ cs,
    float* mu_in, float* mu_not)
{
  __shared__ float4 s_in[256], s_not[256];
  const int tid = threadIdx.x;
  const int c4 = tid & 31;    // float4-column 0..31
  const int rs = tid >> 5;    // row slice 0..7
  const long base = (long)blockIdx.x * 256;
  float4 mi = {0.f, 0.f, 0.f, 0.f}, mn = {0.f, 0.f, 0.f, 0.f};
  const float4* e4 = (const float4*)enc;
  #pragma unroll 4
  for (int it = 0; it < 32; ++it) {
    long r = base + rs + 8L * it;
    if (r < NN) {
      float4 v = e4[r * 32 + c4];
      bool ins = cs[r] > 0;
      mi.x = fmaxf(mi.x, ins ? v.x : 0.f); mi.y = fmaxf(mi.y, ins ? v.y : 0.f);
      mi.z = fmaxf(mi.z, ins ? v.z : 0.f); mi.w = fmaxf(mi.w, ins ? v.w : 0.f);
      mn.x = fmaxf(mn.x, ins ? 0.f : v.x); mn.y = fmaxf(mn.y, ins ? 0.f : v.y);
      mn.z = fmaxf(mn.z, ins ? 0.f : v.z); mn.w = fmaxf(mn.w, ins ? 0.f : v.w);
    }
  }
  s_in[tid] = mi; s_not[tid] = mn;
  __syncthreads();
  if (tid < 32) {
    for (int j = 1; j < 8; ++j) {
      float4 a = s_in[j * 32 + tid], b = s_not[j * 32 + tid];
      mi.x = fmaxf(mi.x, a.x); mi.y = fmaxf(mi.y, a.y);
      mi.z = fmaxf(mi.z, a.z); mi.w = fmaxf(mi.w, a.w);
      mn.x = fmaxf(mn.x, b.x); mn.y = fmaxf(mn.y, b.y);
      mn.z = fmaxf(mn.z, b.z); mn.w = fmaxf(mn.w, b.w);
    }
    // maxima are >= 0 so int-bit compare == float compare
    atomicMax((int*)&mu_in[4 * tid + 0], __float_as_int(mi.x));
    atomicMax((int*)&mu_in[4 * tid + 1], __float_as_int(mi.y));
    atomicMax((int*)&mu_in[4 * tid + 2], __float_as_int(mi.z));
    atomicMax((int*)&mu_in[4 * tid + 3], __float_as_int(mi.w));
    atomicMax((int*)&mu_not[4 * tid + 0], __float_as_int(mn.x));
    atomicMax((int*)&mu_not[4 * tid + 1], __float_as_int(mn.y));
    atomicMax((int*)&mu_not[4 * tid + 2], __float_as_int(mn.z));
    atomicMax((int*)&mu_not[4 * tid + 3], __float_as_int(mn.w));
  }
}

// ---------------- K_mlp: persistent, weights LDS-resident, barrier-free loop -------------
// 512 threads = 8 waves, grid 256, 1 block/CU (LDS-pinned). 16 rows/wave-iter.
// PLAIN __launch_bounds__(512): the backend derives occupancy from the 158.7 KB LDS
// (1 block/CU -> 2 waves/EU -> 256-reg unified budget) and allocates demand (~120),
// exactly as round 1 proved (100 VGPR, zero scratch). Rounds 2-4's second-arg hints
// shrank the budget (128/128/64 arch) and caused 300-700 MB of spill traffic.
// Interleaved per-mt-pair epilogue keeps only 8 accumulator regs live at a time.
// All repacks via __builtin_bit_cast (pure SSA -- no union/local-mem lowering).
__global__ __launch_bounds__(512) void k_mlp(
    const float* __restrict__ enc,
    const float* __restrict__ W1, const float* __restrict__ b1,
    const float* __restrict__ W2, const float* __restrict__ b2,
    const float* __restrict__ W3, const float* __restrict__ b3,
    const float* __restrict__ W4, const float* __restrict__ b4,
    const float* __restrict__ mu_in, const float* __restrict__ mu_not,
    float* __restrict__ eL, float* __restrict__ psum)
{
  __shared__ ushort_t sW1[256 * 136];   // [n1][k=e]   69632 B
  __shared__ ushort_t sW2[128 * 264];   // [n2][k=n1]  67584 B
  __shared__ ushort_t sW3[64 * 136];    // [n3][k=n2]  17408 B
  __shared__ float sC[520];             // c[256]|b2[128]|b3[64]|W4[64]|b4
  __shared__ float sT[512];             // cvec partials

  const int tid = threadIdx.x;

  // ---- one-time staging: fp32 global -> bf16 LDS (transposed; coalesced in n) ----
  for (int idx = tid; idx < 32768; idx += 512) {
    int n = idx & 255, k = idx >> 8;              // n1, e
    sW1[n * 136 + k] = f2bf(W1[(256 + k) * 256 + n]);
  }
  for (int idx = tid; idx < 32768; idx += 512) {
    int n = idx & 127, k = idx >> 7;              // n2, n1
    sW2[n * 264 + k] = f2bf(W2[k * 128 + n]);
  }
  for (int idx = tid; idx < 8192; idx += 512) {
    int n = idx & 63, k = idx >> 6;               // n3, n2
    sW3[n * 136 + k] = f2bf(W3[k * 64 + n]);
  }
  if (tid >= 256 && tid < 384) sC[tid] = b2[tid - 256];
  else if (tid >= 384 && tid < 448) sC[tid] = b3[tid - 384];
  else if (tid >= 448) sC[tid] = W4[tid - 448];
  if (tid == 0) sC[512] = b4[0];
  { // inlined cvec: c[j] = b1[j] + mu_in . W1[0:128,j] + mu_not . W1[128:256,j]
    const int j = tid & 255, h = tid >> 8;        // h = 0..1
    float c = h ? 0.f : b1[j];
    #pragma unroll 8
    for (int e = 64 * h; e < 64 * h + 64; ++e) {
      c += mu_in[e]  * W1[e * 256 + j];
      c += mu_not[e] * W1[(128 + e) * 256 + j];
    }
    sT[tid] = c;
  }
  __syncthreads();
  if (tid < 256) sC[tid] = sT[tid] + sT[tid + 256];
  __syncthreads();   // last block-wide barrier

  const int wave = tid >> 6, lane = tid & 63;
  const int lr = lane & 15, lg = lane >> 4;
  const int wid = blockIdx.x * 8 + wave;          // 0..2047
  const int selhi = lane & 32;
  const int srcLo = lr + ((lane & 16) << 1);      // butterfly partner lanes
  const int srcHi = srcLo + 16;

  const ushort_t* w1p = sW1 + lr * 136 + 8 * lg;  // + mt*2176 + kt*32
  const ushort_t* w2p = sW2 + lr * 264 + 8 * lg;  // + mt*4224 + kt*32
  const ushort_t* w3p = sW3 + lr * 136 + 8 * lg;

  float es = 0.f;
  bf16x8 B1[4];

  // preload + convert first 16-row group (row = wid*16 + lr, always < NN)
  {
    const float4* p = (const float4*)(enc + (size_t)(wid * 16 + lr) * 128);
    #pragma unroll
    for (int kt = 0; kt < 4; ++kt) {
      float4 f0 = p[kt * 8 + lg * 2], f1 = p[kt * 8 + lg * 2 + 1];
      bf16x8 a;
      a[0] = (__bf16)f0.x; a[1] = (__bf16)f0.y; a[2] = (__bf16)f0.z; a[3] = (__bf16)f0.w;
      a[4] = (__bf16)f1.x; a[5] = (__bf16)f1.y; a[6] = (__bf16)f1.z; a[7] = (__bf16)f1.w;
      B1[kt] = a;
    }
  }

  for (int r0 = wid * 16; r0 < NN; r0 += 32768) {
    // ---- L1: mt-pairs with immediate epilogue+butterfly -> B2[p] ----
    bf16x8 B2[8];
    #pragma unroll
    for (int p = 0; p < 8; ++p) {
      f32x4 a0 = (f32x4){0.f, 0.f, 0.f, 0.f}, a1 = (f32x4){0.f, 0.f, 0.f, 0.f};
      #pragma unroll
      for (int kt = 0; kt < 4; ++kt) {
        bf16x8 wA = *(const bf16x8*)(w1p + (2 * p) * 2176 + kt * 32);
        bf16x8 wB = *(const bf16x8*)(w1p + (2 * p + 1) * 2176 + kt * 32);
        a0 = __builtin_amdgcn_mfma_f32_16x16x32_bf16(wA, B1[kt], a0, 0, 0, 0);
        a1 = __builtin_amdgcn_mfma_f32_16x16x32_bf16(wB, B1[kt], a1, 0, 0, 0);
      }
      float4 cb0 = *(const float4*)(sC + 16 * (2 * p) + 4 * lg);
      float4 cb1 = *(const float4*)(sC + 16 * (2 * p + 1) + 4 * lg);
      unsigned q0 = pk2(lrelu(a0[0] + cb0.x), lrelu(a0[1] + cb0.y));
      unsigned q1 = pk2(lrelu(a0[2] + cb0.z), lrelu(a0[3] + cb0.w));
      unsigned q2 = pk2(lrelu(a1[0] + cb1.x), lrelu(a1[1] + cb1.y));
      unsigned q3 = pk2(lrelu(a1[2] + cb1.z), lrelu(a1[3] + cb1.w));
      unsigned w0a = SHF(q0, srcLo), w0b = SHF(q2, srcLo);
      unsigned w1a = SHF(q1, srcLo), w1b = SHF(q3, srcLo);
      unsigned w2a = SHF(q0, srcHi), w2b = SHF(q2, srcHi);
      unsigned w3a = SHF(q1, srcHi), w3b = SHF(q3, srcHi);
      B2[p] = mk8(selhi ? w0b : w0a, selhi ? w1b : w1a,
                  selhi ? w2b : w2a, selhi ? w3b : w3a);
    }
    // ---- prefetch next 16-row group (B1 dead; consumed at loop bottom) ----
    int rn = r0 + 32768; if (rn >= NN) rn = r0;   // last iter: dummy reload
    float4 tA[8];
    {
      const float4* p = (const float4*)(enc + (size_t)(rn + lr) * 128);
      #pragma unroll
      for (int kt = 0; kt < 4; ++kt) {
        tA[2 * kt]     = p[kt * 8 + lg * 2];
        tA[2 * kt + 1] = p[kt * 8 + lg * 2 + 1];
      }
    }
    // ---- L2: mt-pairs -> B3[p] ----
    bf16x8 B3[4];
    #pragma unroll
    for (int p = 0; p < 4; ++p) {
      f32x4 a0 = (f32x4){0.f, 0.f, 0.f, 0.f}, a1 = (f32x4){0.f, 0.f, 0.f, 0.f};
      #pragma unroll
      for (int kt = 0; kt < 8; ++kt) {
        bf16x8 wA = *(const bf16x8*)(w2p + (2 * p) * 4224 + kt * 32);
        bf16x8 wB = *(const bf16x8*)(w2p + (2 * p + 1) * 4224 + kt * 32);
        a0 = __builtin_amdgcn_mfma_f32_16x16x32_bf16(wA, B2[kt], a0, 0, 0, 0);
        a1 = __builtin_amdgcn_mfma_f32_16x16x32_bf16(wB, B2[kt], a1, 0, 0, 0);
      }
      float4 cb0 = *(const float4*)(sC + 256 + 16 * (2 * p) + 4 * lg);
      float4 cb1 = *(const float4*)(sC + 256 + 16 * (2 * p + 1) + 4 * lg);
      unsigned q0 = pk2(lrelu(a0[0] + cb0.x), lrelu(a0[1] + cb0.y));
      unsigned q1 = pk2(lrelu(a0[2] + cb0.z), lrelu(a0[3] + cb0.w));
      unsigned q2 = pk2(lrelu(a1[0] + cb1.x), lrelu(a1[1] + cb1.y));
      unsigned q3 = pk2(lrelu(a1[2] + cb1.z), lrelu(a1[3] + cb1.w));
      unsigned w0a = SHF(q0, srcLo), w0b = SHF(q2, srcLo);
      unsigned w1a = SHF(q1, srcLo), w1b = SHF(q3, srcLo);
      unsigned w2a = SHF(q0, srcHi), w2b = SHF(q2, srcHi);
      unsigned w3a = SHF(q1, srcHi), w3b = SHF(q3, srcHi);
      B3[p] = mk8(selhi ? w0b : w0a, selhi ? w1b : w1a,
                  selhi ? w2b : w2a, selhi ? w3b : w3a);
    }
    // ---- L3 (mt-pairs) + L4 epilogue folded into W4 dot ----
    float dot = 0.f;
    #pragma unroll
    for (int p = 0; p < 2; ++p) {
      f32x4 a0 = (f32x4){0.f, 0.f, 0.f, 0.f}, a1 = (f32x4){0.f, 0.f, 0.f, 0.f};
      #pragma unroll
      for (int kt = 0; kt < 4; ++kt) {
        bf16x8 wA = *(const bf16x8*)(w3p + (2 * p) * 2176 + kt * 32);
        bf16x8 wB = *(const bf16x8*)(w3p + (2 * p + 1) * 2176 + kt * 32);
        a0 = __builtin_amdgcn_mfma_f32_16x16x32_bf16(wA, B3[kt], a0, 0, 0, 0);
        a1 = __builtin_amdgcn_mfma_f32_16x16x32_bf16(wB, B3[kt], a1, 0, 0, 0);
      }
      float4 cb0  = *(const float4*)(sC + 384 + 16 * (2 * p) + 4 * lg);
      float4 cb1  = *(const float4*)(sC + 384 + 16 * (2 * p + 1) + 4 * lg);
      float4 w4v0 = *(const float4*)(sC + 448 + 16 * (2 * p) + 4 * lg);
      float4 w4v1 = *(const float4*)(sC + 448 + 16 * (2 * p + 1) + 4 * lg);
      dot += lrelu(a0[0] + cb0.x) * w4v0.x + lrelu(a0[1] + cb0.y) * w4v0.y
           + lrelu(a0[2] + cb0.z) * w4v0.z + lrelu(a0[3] + cb0.w) * w4v0.w;
      dot += lrelu(a1[0] + cb1.x) * w4v1.x + lrelu(a1[1] + cb1.y) * w4v1.y
           + lrelu(a1[2] + cb1.z) * w4v1.z + lrelu(a1[3] + cb1.w) * w4v1.w;
    }
    dot += __shfl_xor(dot, 16, 64);
    dot += __shfl_xor(dot, 32, 64);
    float ev = expf(dot + sC[512]);
    if (lg == 0) eL[r0 + lr] = ev;
    es += ev;                        // 4x duplicated across lg, scaled at the end
    // ---- convert prefetched rows -> B1 for next iteration ----
    #pragma unroll
    for (int kt = 0; kt < 4; ++kt) {
      float4 f0 = tA[2 * kt], f1 = tA[2 * kt + 1];
      bf16x8 a;
      a[0] = (__bf16)f0.x; a[1] = (__bf16)f0.y; a[2] = (__bf16)f0.z; a[3] = (__bf16)f0.w;
      a[4] = (__bf16)f1.x; a[5] = (__bf16)f1.y; a[6] = (__bf16)f1.z; a[7] = (__bf16)f1.w;
      B1[kt] = a;
    }
  }
  // wave-wide partial softmax denominator (deterministic: one slot per wave)
  #pragma unroll
  for (int off = 1; off < 64; off <<= 1) es += __shfl_xor(es, off, 64);
  if (lane == 0) psum[wid] = 0.25f * es;
}

// ---------------- final reduce + normalize ----------------
__global__ __launch_bounds__(256) void k_finalsum(const float* __restrict__ psum,
                                                  float* __restrict__ scal)
{
  const int tid = threadIdx.x;
  float s = 0.f;
  #pragma unroll
  for (int k = 0; k < 8; ++k) s += psum[tid + k * 256];
  #pragma unroll
  for (int off = 1; off < 64; off <<= 1) s += __shfl_xor(s, off, 64);
  __shared__ float sr[4];
  if ((tid & 63) == 0) sr[tid >> 6] = s;
  __syncthreads();
  if (tid == 0) scal[0] = 1.f / (sr[0] + sr[1] + sr[2] + sr[3]);
}

__global__ __launch_bounds__(256) void k_norm(const float* __restrict__ eL,
                                              const float* __restrict__ scal,
                                              float* __restrict__ out)
{
  const float inv = scal[0];
  const int i = blockIdx.x * 256 + threadIdx.x;
  if (i < NN / 4) {
    float4 v = ((const float4*)eL)[i];
    float4 o = {v.x * inv, v.y * inv, v.z * inv, v.w * inv};
    ((float4*)out)[i] = o;
  }
}

extern "C" void kernel_launch(void* const* d_in, const int* in_sizes, int n_in,
                              void* d_out, int out_size, void* d_ws, size_t ws_size,
                              hipStream_t stream) {
  const float* enc = (const float*)d_in[0];
  const int*   cs  = (const int*)d_in[1];
  const float* W1  = (const float*)d_in[2];
  const float* b1  = (const float*)d_in[3];
  const float* W2  = (const float*)d_in[4];
  const float* b2  = (const float*)d_in[5];
  const float* W3  = (const float*)d_in[6];
  const float* b3  = (const float*)d_in[7];
  const float* W4  = (const float*)d_in[8];
  const float* b4  = (const float*)d_in[9];
  float* out = (float*)d_out;

  char* ws = (char*)d_ws;
  float* mu_in  = (float*)(ws + 0);        // 512 B
  float* mu_not = (float*)(ws + 512);      // 512 B
  float* psum   = (float*)(ws + 2048);     // 2048 floats = 8 KB
  float* scal   = (float*)(ws + 10240);    // 4 B
  float* eLbuf  = (float*)(ws + 12288);    // 2 MB (exp(logit) per row)

  hipMemsetAsync(ws, 0, 1024, stream);  // zero mu_in/mu_not (identity for max >= 0)

  k_colmax<<<dim3(1954), dim3(256), 0, stream>>>(enc, cs, mu_in, mu_not);
  k_mlp<<<dim3(256), dim3(512), 0, stream>>>(enc, W1, b1, W2, b2, W3, b3, W4, b4,
                                             mu_in, mu_not, eLbuf, psum);
  k_finalsum<<<dim3(1), dim3(256), 0, stream>>>(psum, scal);
  k_norm<<<dim3(489), dim3(256), 0, stream>>>(eLbuf, scal, out);
}

// Round 6
// 322.459 us; speedup vs baseline: 4.7304x; 4.0700x over previous
//
#include <hip/hip_runtime.h>
#include <hip/hip_bf16.h>

#define NN 500000
// feats = [mu_in(128) | mu_not(128) | enc(128)]; H1=256, H2=128, H3=64

typedef unsigned short ushort_t;
typedef __attribute__((ext_vector_type(8))) __bf16 bf16x8;
typedef __attribute__((ext_vector_type(2))) __bf16 bf16x2;
typedef __attribute__((ext_vector_type(4))) float f32x4;
typedef __attribute__((ext_vector_type(4))) unsigned uint4v;

__device__ inline ushort_t f2bf(float f) {
  unsigned u = __builtin_bit_cast(unsigned, f);
  return (ushort_t)((u + 0x7FFFu + ((u >> 16) & 1u)) >> 16);
}
__device__ inline float lrelu(float v) { return fmaxf(v, 0.f) + 0.01f * fminf(v, 0.f); }
__device__ inline unsigned pk2(float lo, float hi) {
  bf16x2 v; v[0] = (__bf16)lo; v[1] = (__bf16)hi;
  return __builtin_bit_cast(unsigned, v);
}
__device__ inline bf16x8 mk8(unsigned w0, unsigned w1, unsigned w2, unsigned w3) {
  uint4v u; u.x = w0; u.y = w1; u.z = w2; u.w = w3;
  return __builtin_bit_cast(bf16x8, u);
}
#define SHF(v, s) ((unsigned)__shfl((int)(v), (s), 64))
#define SBAR() __builtin_amdgcn_sched_barrier(0)

// ---------------- K_colmax: masked per-column max over N rows ----------------
__global__ __launch_bounds__(256) void k_colmax(
    const float* __restrict__ enc, const int* __restrict__ cs,
    float* mu_in, float* mu_not)
{
  __shared__ float4 s_in[256], s_not[256];
  const int tid = threadIdx.x;
  const int c4 = tid & 31;    // float4-column 0..31
  const int rs = tid >> 5;    // row slice 0..7
  const long base = (long)blockIdx.x * 256;
  float4 mi = {0.f, 0.f, 0.f, 0.f}, mn = {0.f, 0.f, 0.f, 0.f};
  const float4* e4 = (const float4*)enc;
  #pragma unroll 4
  for (int it = 0; it < 32; ++it) {
    long r = base + rs + 8L * it;
    if (r < NN) {
      float4 v = e4[r * 32 + c4];
      bool ins = cs[r] > 0;
      mi.x = fmaxf(mi.x, ins ? v.x : 0.f); mi.y = fmaxf(mi.y, ins ? v.y : 0.f);
      mi.z = fmaxf(mi.z, ins ? v.z : 0.f); mi.w = fmaxf(mi.w, ins ? v.w : 0.f);
      mn.x = fmaxf(mn.x, ins ? 0.f : v.x); mn.y = fmaxf(mn.y, ins ? 0.f : v.y);
      mn.z = fmaxf(mn.z, ins ? 0.f : v.z); mn.w = fmaxf(mn.w, ins ? 0.f : v.w);
    }
  }
  s_in[tid] = mi; s_not[tid] = mn;
  __syncthreads();
  if (tid < 32) {
    for (int j = 1; j < 8; ++j) {
      float4 a = s_in[j * 32 + tid], b = s_not[j * 32 + tid];
      mi.x = fmaxf(mi.x, a.x); mi.y = fmaxf(mi.y, a.y);
      mi.z = fmaxf(mi.z, a.z); mi.w = fmaxf(mi.w, a.w);
      mn.x = fmaxf(mn.x, b.x); mn.y = fmaxf(mn.y, b.y);
      mn.z = fmaxf(mn.z, b.z); mn.w = fmaxf(mn.w, b.w);
    }
    // maxima are >= 0 so int-bit compare == float compare
    atomicMax((int*)&mu_in[4 * tid + 0], __float_as_int(mi.x));
    atomicMax((int*)&mu_in[4 * tid + 1], __float_as_int(mi.y));
    atomicMax((int*)&mu_in[4 * tid + 2], __float_as_int(mi.z));
    atomicMax((int*)&mu_in[4 * tid + 3], __float_as_int(mi.w));
    atomicMax((int*)&mu_not[4 * tid + 0], __float_as_int(mn.x));
    atomicMax((int*)&mu_not[4 * tid + 1], __float_as_int(mn.y));
    atomicMax((int*)&mu_not[4 * tid + 2], __float_as_int(mn.z));
    atomicMax((int*)&mu_not[4 * tid + 3], __float_as_int(mn.w));
  }
}

// ---------------- K_mlp: persistent, weights LDS-resident, barrier-free loop -------------
// 512 threads = 8 waves, grid 256, 1 block/CU (LDS-pinned). 16 rows/wave-iter.
// amdgpu_waves_per_eu(2,2): request the 2-waves/EU register budget (256/wave)
// explicitly -- every launch_bounds variant so far produced a 128-arch cap.
// Demand-side fixes: enc prefetch issued AFTER L2 (tA overlaps only L3/L4, not the
// fat L2 phase) and sched_barrier(0) at phase boundaries so the scheduler cannot
// hoist a whole phase's ds_reads (the +60-reg inflation that caused the spill).
__global__ __launch_bounds__(512)
__attribute__((amdgpu_waves_per_eu(2, 2)))
void k_mlp(
    const float* __restrict__ enc,
    const float* __restrict__ W1, const float* __restrict__ b1,
    const float* __restrict__ W2, const float* __restrict__ b2,
    const float* __restrict__ W3, const float* __restrict__ b3,
    const float* __restrict__ W4, const float* __restrict__ b4,
    const float* __restrict__ mu_in, const float* __restrict__ mu_not,
    float* __restrict__ eL, float* __restrict__ psum)
{
  __shared__ ushort_t sW1[256 * 136];   // [n1][k=e]   69632 B
  __shared__ ushort_t sW2[128 * 264];   // [n2][k=n1]  67584 B
  __shared__ ushort_t sW3[64 * 136];    // [n3][k=n2]  17408 B
  __shared__ float sC[520];             // c[256]|b2[128]|b3[64]|W4[64]|b4
  __shared__ float sT[512];             // cvec partials

  const int tid = threadIdx.x;

  // ---- one-time staging: fp32 global -> bf16 LDS (transposed; coalesced in n) ----
  for (int idx = tid; idx < 32768; idx += 512) {
    int n = idx & 255, k = idx >> 8;              // n1, e
    sW1[n * 136 + k] = f2bf(W1[(256 + k) * 256 + n]);
  }
  for (int idx = tid; idx < 32768; idx += 512) {
    int n = idx & 127, k = idx >> 7;              // n2, n1
    sW2[n * 264 + k] = f2bf(W2[k * 128 + n]);
  }
  for (int idx = tid; idx < 8192; idx += 512) {
    int n = idx & 63, k = idx >> 6;               // n3, n2
    sW3[n * 136 + k] = f2bf(W3[k * 64 + n]);
  }
  if (tid >= 256 && tid < 384) sC[tid] = b2[tid - 256];
  else if (tid >= 384 && tid < 448) sC[tid] = b3[tid - 384];
  else if (tid >= 448) sC[tid] = W4[tid - 448];
  if (tid == 0) sC[512] = b4[0];
  { // inlined cvec: c[j] = b1[j] + mu_in . W1[0:128,j] + mu_not . W1[128:256,j]
    const int j = tid & 255, h = tid >> 8;        // h = 0..1
    float c = h ? 0.f : b1[j];
    #pragma unroll 8
    for (int e = 64 * h; e < 64 * h + 64; ++e) {
      c += mu_in[e]  * W1[e * 256 + j];
      c += mu_not[e] * W1[(128 + e) * 256 + j];
    }
    sT[tid] = c;
  }
  __syncthreads();
  if (tid < 256) sC[tid] = sT[tid] + sT[tid + 256];
  __syncthreads();   // last block-wide barrier

  const int wave = tid >> 6, lane = tid & 63;
  const int lr = lane & 15, lg = lane >> 4;
  const int wid = blockIdx.x * 8 + wave;          // 0..2047
  const int selhi = lane & 32;
  const int srcLo = lr + ((lane & 16) << 1);      // butterfly partner lanes
  const int srcHi = srcLo + 16;

  const ushort_t* w1p = sW1 + lr * 136 + 8 * lg;  // + mt*2176 + kt*32
  const ushort_t* w2p = sW2 + lr * 264 + 8 * lg;  // + mt*4224 + kt*32
  const ushort_t* w3p = sW3 + lr * 136 + 8 * lg;

  float es = 0.f;
  bf16x8 B1[4];

  // preload + convert first 16-row group (row = wid*16 + lr, always < NN)
  {
    const float4* p = (const float4*)(enc + (size_t)(wid * 16 + lr) * 128);
    #pragma unroll
    for (int kt = 0; kt < 4; ++kt) {
      float4 f0 = p[kt * 8 + lg * 2], f1 = p[kt * 8 + lg * 2 + 1];
      bf16x8 a;
      a[0] = (__bf16)f0.x; a[1] = (__bf16)f0.y; a[2] = (__bf16)f0.z; a[3] = (__bf16)f0.w;
      a[4] = (__bf16)f1.x; a[5] = (__bf16)f1.y; a[6] = (__bf16)f1.z; a[7] = (__bf16)f1.w;
      B1[kt] = a;
    }
  }

  for (int r0 = wid * 16; r0 < NN; r0 += 32768) {
    // ---- L1: mt-pairs with immediate epilogue+butterfly -> B2[p] ----
    bf16x8 B2[8];
    #pragma unroll
    for (int p = 0; p < 8; ++p) {
      f32x4 a0 = (f32x4){0.f, 0.f, 0.f, 0.f}, a1 = (f32x4){0.f, 0.f, 0.f, 0.f};
      #pragma unroll
      for (int kt = 0; kt < 4; ++kt) {
        bf16x8 wA = *(const bf16x8*)(w1p + (2 * p) * 2176 + kt * 32);
        bf16x8 wB = *(const bf16x8*)(w1p + (2 * p + 1) * 2176 + kt * 32);
        a0 = __builtin_amdgcn_mfma_f32_16x16x32_bf16(wA, B1[kt], a0, 0, 0, 0);
        a1 = __builtin_amdgcn_mfma_f32_16x16x32_bf16(wB, B1[kt], a1, 0, 0, 0);
      }
      float4 cb0 = *(const float4*)(sC + 16 * (2 * p) + 4 * lg);
      float4 cb1 = *(const float4*)(sC + 16 * (2 * p + 1) + 4 * lg);
      unsigned q0 = pk2(lrelu(a0[0] + cb0.x), lrelu(a0[1] + cb0.y));
      unsigned q1 = pk2(lrelu(a0[2] + cb0.z), lrelu(a0[3] + cb0.w));
      unsigned q2 = pk2(lrelu(a1[0] + cb1.x), lrelu(a1[1] + cb1.y));
      unsigned q3 = pk2(lrelu(a1[2] + cb1.z), lrelu(a1[3] + cb1.w));
      unsigned w0a = SHF(q0, srcLo), w0b = SHF(q2, srcLo);
      unsigned w1a = SHF(q1, srcLo), w1b = SHF(q3, srcLo);
      unsigned w2a = SHF(q0, srcHi), w2b = SHF(q2, srcHi);
      unsigned w3a = SHF(q1, srcHi), w3b = SHF(q3, srcHi);
      B2[p] = mk8(selhi ? w0b : w0a, selhi ? w1b : w1a,
                  selhi ? w2b : w2a, selhi ? w3b : w3a);
    }
    SBAR();   // phase fence: keep L2's ds_reads from hoisting into L1
    // ---- L2: mt-pairs -> B3[p] ----
    bf16x8 B3[4];
    #pragma unroll
    for (int p = 0; p < 4; ++p) {
      f32x4 a0 = (f32x4){0.f, 0.f, 0.f, 0.f}, a1 = (f32x4){0.f, 0.f, 0.f, 0.f};
      #pragma unroll
      for (int kt = 0; kt < 8; ++kt) {
        bf16x8 wA = *(const bf16x8*)(w2p + (2 * p) * 4224 + kt * 32);
        bf16x8 wB = *(const bf16x8*)(w2p + (2 * p + 1) * 4224 + kt * 32);
        a0 = __builtin_amdgcn_mfma_f32_16x16x32_bf16(wA, B2[kt], a0, 0, 0, 0);
        a1 = __builtin_amdgcn_mfma_f32_16x16x32_bf16(wB, B2[kt], a1, 0, 0, 0);
      }
      float4 cb0 = *(const float4*)(sC + 256 + 16 * (2 * p) + 4 * lg);
      float4 cb1 = *(const float4*)(sC + 256 + 16 * (2 * p + 1) + 4 * lg);
      unsigned q0 = pk2(lrelu(a0[0] + cb0.x), lrelu(a0[1] + cb0.y));
      unsigned q1 = pk2(lrelu(a0[2] + cb0.z), lrelu(a0[3] + cb0.w));
      unsigned q2 = pk2(lrelu(a1[0] + cb1.x), lrelu(a1[1] + cb1.y));
      unsigned q3 = pk2(lrelu(a1[2] + cb1.z), lrelu(a1[3] + cb1.w));
      unsigned w0a = SHF(q0, srcLo), w0b = SHF(q2, srcLo);
      unsigned w1a = SHF(q1, srcLo), w1b = SHF(q3, srcLo);
      unsigned w2a = SHF(q0, srcHi), w2b = SHF(q2, srcHi);
      unsigned w3a = SHF(q1, srcHi), w3b = SHF(q3, srcHi);
      B3[p] = mk8(selhi ? w0b : w0a, selhi ? w1b : w1a,
                  selhi ? w2b : w2a, selhi ? w3b : w3a);
    }
    SBAR();   // phase fence
    // ---- prefetch next 16-row group: issue here, consume at loop bottom.
    //      tA is live only across L3/L4 (the thin phase), not across L2.
    int rn = r0 + 32768; if (rn >= NN) rn = r0;   // last iter: dummy reload
    float4 tA[8];
    {
      const float4* p = (const float4*)(enc + (size_t)(rn + lr) * 128);
      #pragma unroll
      for (int kt = 0; kt < 4; ++kt) {
        tA[2 * kt]     = p[kt * 8 + lg * 2];
        tA[2 * kt + 1] = p[kt * 8 + lg * 2 + 1];
      }
    }
    SBAR();   // pin the load-issue position (do not sink into L3)
    // ---- L3 (mt-pairs) + L4 epilogue folded into W4 dot ----
    float dot = 0.f;
    #pragma unroll
    for (int p = 0; p < 2; ++p) {
      f32x4 a0 = (f32x4){0.f, 0.f, 0.f, 0.f}, a1 = (f32x4){0.f, 0.f, 0.f, 0.f};
      #pragma unroll
      for (int kt = 0; kt < 4; ++kt) {
        bf16x8 wA = *(const bf16x8*)(w3p + (2 * p) * 2176 + kt * 32);
        bf16x8 wB = *(const bf16x8*)(w3p + (2 * p + 1) * 2176 + kt * 32);
        a0 = __builtin_amdgcn_mfma_f32_16x16x32_bf16(wA, B3[kt], a0, 0, 0, 0);
        a1 = __builtin_amdgcn_mfma_f32_16x16x32_bf16(wB, B3[kt], a1, 0, 0, 0);
      }
      float4 cb0  = *(const float4*)(sC + 384 + 16 * (2 * p) + 4 * lg);
      float4 cb1  = *(const float4*)(sC + 384 + 16 * (2 * p + 1) + 4 * lg);
      float4 w4v0 = *(const float4*)(sC + 448 + 16 * (2 * p) + 4 * lg);
      float4 w4v1 = *(const float4*)(sC + 448 + 16 * (2 * p + 1) + 4 * lg);
      dot += lrelu(a0[0] + cb0.x) * w4v0.x + lrelu(a0[1] + cb0.y) * w4v0.y
           + lrelu(a0[2] + cb0.z) * w4v0.z + lrelu(a0[3] + cb0.w) * w4v0.w;
      dot += lrelu(a1[0] + cb1.x) * w4v1.x + lrelu(a1[1] + cb1.y) * w4v1.y
           + lrelu(a1[2] + cb1.z) * w4v1.z + lrelu(a1[3] + cb1.w) * w4v1.w;
    }
    dot += __shfl_xor(dot, 16, 64);
    dot += __shfl_xor(dot, 32, 64);
    float ev = expf(dot + sC[512]);
    if (lg == 0) eL[r0 + lr] = ev;
    es += ev;                        // 4x duplicated across lg, scaled at the end
    // ---- convert prefetched rows -> B1 for next iteration ----
    #pragma unroll
    for (int kt = 0; kt < 4; ++kt) {
      float4 f0 = tA[2 * kt], f1 = tA[2 * kt + 1];
      bf16x8 a;
      a[0] = (__bf16)f0.x; a[1] = (__bf16)f0.y; a[2] = (__bf16)f0.z; a[3] = (__bf16)f0.w;
      a[4] = (__bf16)f1.x; a[5] = (__bf16)f1.y; a[6] = (__bf16)f1.z; a[7] = (__bf16)f1.w;
      B1[kt] = a;
    }
  }
  // wave-wide partial softmax denominator (deterministic: one slot per wave)
  #pragma unroll
  for (int off = 1; off < 64; off <<= 1) es += __shfl_xor(es, off, 64);
  if (lane == 0) psum[wid] = 0.25f * es;
}

// ---------------- final reduce + normalize ----------------
__global__ __launch_bounds__(256) void k_finalsum(const float* __restrict__ psum,
                                                  float* __restrict__ scal)
{
  const int tid = threadIdx.x;
  float s = 0.f;
  #pragma unroll
  for (int k = 0; k < 8; ++k) s += psum[tid + k * 256];
  #pragma unroll
  for (int off = 1; off < 64; off <<= 1) s += __shfl_xor(s, off, 64);
  __shared__ float sr[4];
  if ((tid & 63) == 0) sr[tid >> 6] = s;
  __syncthreads();
  if (tid == 0) scal[0] = 1.f / (sr[0] + sr[1] + sr[2] + sr[3]);
}

__global__ __launch_bounds__(256) void k_norm(const float* __restrict__ eL,
                                              const float* __restrict__ scal,
                                              float* __restrict__ out)
{
  const float inv = scal[0];
  const int i = blockIdx.x * 256 + threadIdx.x;
  if (i < NN / 4) {
    float4 v = ((const float4*)eL)[i];
    float4 o = {v.x * inv, v.y * inv, v.z * inv, v.w * inv};
    ((float4*)out)[i] = o;
  }
}

extern "C" void kernel_launch(void* const* d_in, const int* in_sizes, int n_in,
                              void* d_out, int out_size, void* d_ws, size_t ws_size,
                              hipStream_t stream) {
  const float* enc = (const float*)d_in[0];
  const int*   cs  = (const int*)d_in[1];
  const float* W1  = (const float*)d_in[2];
  const float* b1  = (const float*)d_in[3];
  const float* W2  = (const float*)d_in[4];
  const float* b2  = (const float*)d_in[5];
  const float* W3  = (const float*)d_in[6];
  const float* b3  = (const float*)d_in[7];
  const float* W4  = (const float*)d_in[8];
  const float* b4  = (const float*)d_in[9];
  float* out = (float*)d_out;

  char* ws = (char*)d_ws;
  float* mu_in  = (float*)(ws + 0);        // 512 B
  float* mu_not = (float*)(ws + 512);      // 512 B
  float* psum   = (float*)(ws + 2048);     // 2048 floats = 8 KB
  float* scal   = (float*)(ws + 10240);    // 4 B
  float* eLbuf  = (float*)(ws + 12288);    // 2 MB (exp(logit) per row)

  hipMemsetAsync(ws, 0, 1024, stream);  // zero mu_in/mu_not (identity for max >= 0)

  k_colmax<<<dim3(1954), dim3(256), 0, stream>>>(enc, cs, mu_in, mu_not);
  k_mlp<<<dim3(256), dim3(512), 0, stream>>>(enc, W1, b1, W2, b2, W3, b3, W4, b4,
                                             mu_in, mu_not, eLbuf, psum);
  k_finalsum<<<dim3(1), dim3(256), 0, stream>>>(psum, scal);
  k_norm<<<dim3(489), dim3(256), 0, stream>>>(eLbuf, scal, out);
}